// Round 18
// baseline (263.959 us; speedup 1.0000x reference)
//
#include <hip/hip_runtime.h>
#include <hip/hip_bf16.h>

#define DD 128

typedef __attribute__((ext_vector_type(8))) short short8;
typedef __attribute__((ext_vector_type(4))) float f32x4;
typedef __attribute__((ext_vector_type(2))) float f32x2;

static __device__ __forceinline__ int gtid() {
    return blockIdx.x * blockDim.x + threadIdx.x;
}

static __device__ __forceinline__ ushort f2bfu(float f) {
    __hip_bfloat16 h = __float2bfloat16(f);
    return *reinterpret_cast<ushort*>(&h);
}

// ---- fp8 e4m3fn encode/decode (manual fallback, RNE, subnormal-correct) ----
static __device__ __forceinline__ unsigned int fp8e(float f) {
    unsigned int s = (__float_as_uint(f) >> 31) << 7;
    float a = fabsf(f);
    if (a < 0.015625f) return s | (unsigned int)rintf(a * 512.0f);
    unsigned int u = __float_as_uint(a);
    u += 0x0007FFFFu + ((u >> 20) & 1u);
    unsigned int e8 = (u >> 23) - 120u;
    unsigned int m = (u >> 20) & 7u;
    if (e8 > 15u || (e8 == 15u && m == 7u)) return s | 0x7Eu;
    return s | (e8 << 3) | m;
}

static __device__ __forceinline__ float fp8d(unsigned int b) {
    unsigned int t = b & 0x7Fu;
    float v = (t >= 8u) ? __uint_as_float((t << 20) + 0x3C000000u)
                        : (float)t * 0.001953125f;
    return (b & 0x80u) ? -v : v;
}

static __device__ __forceinline__ unsigned int pk8x2(float a, float b) {
#if __has_builtin(__builtin_amdgcn_cvt_pk_fp8_f32)
    return (unsigned int)__builtin_amdgcn_cvt_pk_fp8_f32(a, b, 0, false);
#else
    return fp8e(a) | (fp8e(b) << 8);
#endif
}

static __device__ __forceinline__ unsigned int pk8x4(float a, float b, float c, float d) {
#if __has_builtin(__builtin_amdgcn_cvt_pk_fp8_f32)
    int v = __builtin_amdgcn_cvt_pk_fp8_f32(a, b, 0, false);
    v = __builtin_amdgcn_cvt_pk_fp8_f32(c, d, v, true);
    return (unsigned int)v;
#else
    return fp8e(a) | (fp8e(b) << 8) | (fp8e(c) << 16) | (fp8e(d) << 24);
#endif
}

static __device__ __forceinline__ void fp8x4_dec(unsigned int u, float* f) {
#if __has_builtin(__builtin_amdgcn_cvt_pk_f32_fp8)
    f32x2 lo = __builtin_amdgcn_cvt_pk_f32_fp8((int)u, false);
    f32x2 hi = __builtin_amdgcn_cvt_pk_f32_fp8((int)u, true);
    f[0] = lo[0]; f[1] = lo[1]; f[2] = hi[0]; f[3] = hi[1];
#else
    f[0] = fp8d(u & 0xFFu);
    f[1] = fp8d((u >> 8) & 0xFFu);
    f[2] = fp8d((u >> 16) & 0xFFu);
    f[3] = fp8d((u >> 24) & 0xFFu);
#endif
}

// ---------- degree / CSR build ----------

__global__ void count_kernel(int* __restrict__ counts, const int* __restrict__ dst, int e) {
    int i = gtid();
    if (i < e) atomicAdd(&counts[dst[i]], 1);
}

__global__ __launch_bounds__(256) void scan_blocks(const int* __restrict__ counts,
                                                   int* __restrict__ rowptr,
                                                   int* __restrict__ partial,
                                                   float* __restrict__ dinv, int n) {
    __shared__ int s[256];
    int i = blockIdx.x * 256 + threadIdx.x;
    int v = (i < n) ? counts[i] : 0;
    if (i < n) dinv[i] = rsqrtf(1.0f + (float)v);
    s[threadIdx.x] = v;
    __syncthreads();
    for (int off = 1; off < 256; off <<= 1) {
        int t = (threadIdx.x >= off) ? s[threadIdx.x - off] : 0;
        __syncthreads();
        s[threadIdx.x] += t;
        __syncthreads();
    }
    if (i < n) rowptr[i] = s[threadIdx.x] - v;
    if (threadIdx.x == 255) partial[blockIdx.x] = s[255];
}

__global__ __launch_bounds__(256) void scan_partials(int* __restrict__ partial,
                                                     int* __restrict__ partial2, int nb) {
    __shared__ int s[256];
    int v = (threadIdx.x < nb) ? partial[threadIdx.x] : 0;
    s[threadIdx.x] = v;
    __syncthreads();
    for (int off = 1; off < 256; off <<= 1) {
        int t = (threadIdx.x >= off) ? s[threadIdx.x - off] : 0;
        __syncthreads();
        s[threadIdx.x] += t;
        __syncthreads();
    }
    partial2[threadIdx.x] = s[threadIdx.x] - v;
}

__global__ __launch_bounds__(256) void add_offsets(int* __restrict__ rowptr,
                                                   int* __restrict__ cursor,
                                                   const int* __restrict__ partial2,
                                                   int n, int e) {
    int i = blockIdx.x * 256 + threadIdx.x;
    if (i < n) {
        int r = rowptr[i] + partial2[blockIdx.x];
        rowptr[i] = r;
        cursor[i] = r;
        if (i == n - 1) rowptr[n] = e;
    }
}

// dst-windowed scatter (R17)
__global__ __launch_bounds__(256) void fill_kernel(
    const int* __restrict__ ei, int* __restrict__ cursor,
    ushort* __restrict__ csr_src, int e, int n, int blocksPerPart) {
    int part = blockIdx.x & 7;
    int blk = blockIdx.x >> 3;
    int lo = (int)(((long)n * part) >> 3);
    int hi = (int)(((long)n * (part + 1)) >> 3);
    int stride = blocksPerPart * 256;
    for (int i = blk * 256 + threadIdx.x; i < e; i += stride) {
        int d = ei[e + i];
        if (d < lo || d >= hi) continue;
        int s = ei[i];
        int pos = atomicAdd(&cursor[d], 1);
        csr_src[pos] = (ushort)s;
    }
}

// ---------- x -> fp8 (vectorized: 8 elems/thread) ----------
__global__ void cvt_kernel(const float* __restrict__ x, unsigned char* __restrict__ xq, size_t m8) {
    size_t i = (size_t)blockIdx.x * blockDim.x + threadIdx.x;
    if (i >= m8) return;
    const float4* xp = reinterpret_cast<const float4*>(x + i * 8);
    float4 a = xp[0], b = xp[1];
    uint2 q;
    q.x = pk8x4(a.x, a.y, a.z, a.w);
    q.y = pk8x4(b.x, b.y, b.z, b.w);
    *reinterpret_cast<uint2*>(xq + i * 8) = q;
}

// ---------- W -> bf16 MFMA B-fragment order ----------
__global__ __launch_bounds__(256) void wpack_kernel(const float* __restrict__ gcn_w,
                                                    ushort* __restrict__ wfrag) {
    int tid = blockIdx.x * 256 + threadIdx.x;
    if (tid >= 3 * 4 * 8 * 64) return;
    int lane = tid & 63;
    int c = (tid >> 6) & 7;
    int s = (tid >> 9) & 3;
    int l = tid >> 11;
    const float* W = gcn_w + (size_t)l * 128 * 128;
    int col = c * 16 + (lane & 15);
    int k0 = s * 32 + (lane >> 4) * 8;
    ushort u[8];
#pragma unroll
    for (int j = 0; j < 8; ++j) {
        u[j] = f2bfu(W[(size_t)(k0 + j) * 128 + col]);
    }
    *reinterpret_cast<uint4*>(wfrag + (size_t)tid * 8) = *reinterpret_cast<const uint4*>(u);
}

// ---------- fused layer: aggregate (fp8 gather) -> LDS -> MFMA GEMM -> zq/zqw ----------
// block = 256 threads = 4 waves = 16 rows (3125 blocks, exact).
// Phase 1: wave w aggregates rows w*4..w*4+3 into swizzled LDS (bf16).
// Phase 2: all 4 waves gemm the 16-row tile; wave w owns cols w*32..+32.
// LDS swizzle: physical_byte(row, bo) = row*256 + (bo ^ ((row&7)<<4))
__global__ __launch_bounds__(256) void layer_fused_kernel(
    const unsigned char* __restrict__ srcq, int srcStride,
    const int* __restrict__ rowptr, const ushort* __restrict__ csr_src,
    const float* __restrict__ dinv, const ushort* __restrict__ wfrag,
    const float* __restrict__ bias, const float* __restrict__ pwsl,
    unsigned char* __restrict__ zq_sl, unsigned char* __restrict__ zqw_sl, int n) {
    __shared__ unsigned char ah[16 * 256];
    int lane = threadIdx.x & 63;
    int wid = threadIdx.x >> 6;   // 0..3
    int row0 = blockIdx.x * 16;

    // preload B fragments (held through both phases)
    short8 b0[4], b1[4];
    int c0 = wid * 2;
#pragma unroll
    for (int s = 0; s < 4; ++s) {
        b0[s] = *reinterpret_cast<const short8*>(wfrag + ((size_t)(s * 8 + c0) * 64 + lane) * 8);
        b1[s] = *reinterpret_cast<const short8*>(wfrag + ((size_t)(s * 8 + c0 + 1) * 64 + lane) * 8);
    }

    // ---- phase 1: aggregate 4 rows ----
    int g = lane >> 3;   // edge slot 0..7
    int c = lane & 7;    // feature chunk (16 feats)
#pragma unroll
    for (int t = 0; t < 4; ++t) {
        int lr = wid * 4 + t;
        int row = row0 + lr;
        int j0 = rowptr[row], j1 = rowptr[row + 1];
        float dr = dinv[row];
        float acc[16];
#pragma unroll
        for (int k = 0; k < 16; ++k) acc[k] = 0.f;
        for (int j = j0 + g; j < j1; j += 8) {
            int s = (int)csr_src[j];
            float cf = dinv[s] * dr;
            uint4 v = *reinterpret_cast<const uint4*>(srcq + (size_t)s * srcStride + c * 16);
            float f[16];
            fp8x4_dec(v.x, f);
            fp8x4_dec(v.y, f + 4);
            fp8x4_dec(v.z, f + 8);
            fp8x4_dec(v.w, f + 12);
#pragma unroll
            for (int k = 0; k < 16; ++k) acc[k] = fmaf(cf, f[k], acc[k]);
        }
#pragma unroll
        for (int k = 0; k < 16; ++k) {
            acc[k] += __shfl_xor(acc[k], 8);
            acc[k] += __shfl_xor(acc[k], 16);
            acc[k] += __shfl_xor(acc[k], 32);
        }
        float d2 = dr * dr;
        uint4 sv = *reinterpret_cast<const uint4*>(srcq + (size_t)row * srcStride + c * 16);
        float sf[16];
        fp8x4_dec(sv.x, sf);
        fp8x4_dec(sv.y, sf + 4);
        fp8x4_dec(sv.z, sf + 8);
        fp8x4_dec(sv.w, sf + 12);
#pragma unroll
        for (int k = 0; k < 16; ++k) acc[k] = fmaf(d2, sf[k], acc[k]);
        if (g == 0) {
            unsigned int pk[8];
#pragma unroll
            for (int q = 0; q < 8; ++q) {
                pk[q] = (unsigned int)f2bfu(acc[2 * q]) | ((unsigned int)f2bfu(acc[2 * q + 1]) << 16);
            }
            int swz = (lr & 7) << 4;
            int bo = c * 32;
            *reinterpret_cast<uint4*>(ah + lr * 256 + (bo ^ swz)) =
                *reinterpret_cast<const uint4*>(pk);
            *reinterpret_cast<uint4*>(ah + lr * 256 + ((bo + 16) ^ swz)) =
                *reinterpret_cast<const uint4*>(pk + 4);
        }
    }
    __syncthreads();

    // ---- phase 2: 16-row MFMA tile from LDS ----
    int rlo = lane & 15;
    int kg = lane >> 4;
    int swzr = (rlo & 7) << 4;
    const unsigned char* arow = ah + rlo * 256;
    short8 a0 = *reinterpret_cast<const short8*>(arow + ((kg * 16) ^ swzr));
    short8 a1 = *reinterpret_cast<const short8*>(arow + ((kg * 16 + 64) ^ swzr));
    short8 a2 = *reinterpret_cast<const short8*>(arow + ((kg * 16 + 128) ^ swzr));
    short8 a3 = *reinterpret_cast<const short8*>(arow + ((kg * 16 + 192) ^ swzr));
    f32x4 acc0 = {0.f, 0.f, 0.f, 0.f};
    f32x4 acc1 = {0.f, 0.f, 0.f, 0.f};
    acc0 = __builtin_amdgcn_mfma_f32_16x16x32_bf16(a0, b0[0], acc0, 0, 0, 0);
    acc1 = __builtin_amdgcn_mfma_f32_16x16x32_bf16(a0, b1[0], acc1, 0, 0, 0);
    acc0 = __builtin_amdgcn_mfma_f32_16x16x32_bf16(a1, b0[1], acc0, 0, 0, 0);
    acc1 = __builtin_amdgcn_mfma_f32_16x16x32_bf16(a1, b1[1], acc1, 0, 0, 0);
    acc0 = __builtin_amdgcn_mfma_f32_16x16x32_bf16(a2, b0[2], acc0, 0, 0, 0);
    acc1 = __builtin_amdgcn_mfma_f32_16x16x32_bf16(a2, b1[2], acc1, 0, 0, 0);
    acc0 = __builtin_amdgcn_mfma_f32_16x16x32_bf16(a3, b0[3], acc0, 0, 0, 0);
    acc1 = __builtin_amdgcn_mfma_f32_16x16x32_bf16(a3, b1[3], acc1, 0, 0, 0);

    int col0 = wid * 32 + rlo;
    float bias0 = bias[col0], bias1 = bias[col0 + 16];
    float pw0 = pwsl[col0] * 8.0f, pw1 = pwsl[col0 + 16] * 8.0f;
    int rowBase = row0 + kg * 4;
#pragma unroll
    for (int r = 0; r < 4; ++r) {
        float v0 = fmaxf(acc0[r] + bias0, 0.f);
        float v1 = fmaxf(acc1[r] + bias1, 0.f);
        unsigned int q = pk8x2(v0, v1);
        unsigned char* zr = zq_sl + (size_t)(rowBase + r) * 384 + col0;
        zr[0] = (unsigned char)(q & 0xFFu);
        zr[16] = (unsigned char)((q >> 8) & 0xFFu);
        unsigned int w = pk8x2(v0 * pw0, v1 * pw1);
        unsigned char* wr = zqw_sl + (size_t)(rowBase + r) * 384 + col0;
        wr[0] = (unsigned char)(w & 0xFFu);
        wr[16] = (unsigned char)((w >> 8) & 0xFFu);
    }
}

// ---------- loss: fp8 MFMA diagonal dot ----------
__global__ __launch_bounds__(256) void loss_mfma_kernel(
    const unsigned char* __restrict__ zq, const unsigned char* __restrict__ zqw,
    const int* __restrict__ pos, const int* __restrict__ neg,
    const float* __restrict__ pb, float* __restrict__ partialOut,
    int p, float inv_total) {
    __shared__ float red[4];
    int lane = threadIdx.x & 63;
    int wv = threadIdx.x >> 6;
    int pairBase = (blockIdx.x * 4 + wv) * 16;
    float term = 0.f;
    if (pairBase < 2 * p) {
        int m = lane & 15;
        int kg = lane >> 4;
        int pi = pairBase + m;
        int pic = (pi < 2 * p) ? pi : (2 * p - 1);
        bool isneg = (pic >= p);
        const int* pr = isneg ? neg : pos;
        int idx = isneg ? (pic - p) : pic;
        int a = pr[idx];
        int b = pr[p + idx];
        const long* pa = reinterpret_cast<const long*>(zq + (size_t)a * 384) + kg;
        const long* pbw = reinterpret_cast<const long*>(zqw + (size_t)b * 384) + kg;
        long av[12], bv[12];
#pragma unroll
        for (int s = 0; s < 12; ++s) av[s] = pa[s * 4];
#pragma unroll
        for (int s = 0; s < 12; ++s) bv[s] = pbw[s * 4];
        f32x4 acc = {0.f, 0.f, 0.f, 0.f};
#pragma unroll
        for (int s = 0; s < 12; ++s) {
            acc = __builtin_amdgcn_mfma_f32_16x16x32_fp8_fp8(av[s], bv[s], acc, 0, 0, 0);
        }
        bool isdiag = (lane >> 4) == ((lane & 15) >> 2);
        int r2 = lane & 3;
        float v = (r2 == 0) ? acc[0] : (r2 == 1) ? acc[1] : (r2 == 2) ? acc[2] : acc[3];
        if (isdiag && pi < 2 * p) {
            float logit = v * 0.125f + pb[0];
            float t = isneg ? logit : -logit;
            term = (fmaxf(t, 0.f) + log1pf(expf(-fabsf(t)))) * inv_total;
        }
    }
#pragma unroll
    for (int off = 1; off < 64; off <<= 1) term += __shfl_xor(term, off);
    if (lane == 0) red[wv] = term;
    __syncthreads();
    if (threadIdx.x == 0) partialOut[blockIdx.x] = red[0] + red[1] + red[2] + red[3];
}

__global__ __launch_bounds__(256) void loss_reduce_kernel(
    const float* __restrict__ partial, float* __restrict__ out, int m) {
    __shared__ float s[256];
    float a = 0.f;
    for (int i = threadIdx.x; i < m; i += 256) a += partial[i];
    s[threadIdx.x] = a;
    __syncthreads();
    for (int off = 128; off > 0; off >>= 1) {
        if (threadIdx.x < off) s[threadIdx.x] += s[threadIdx.x + off];
        __syncthreads();
    }
    if (threadIdx.x == 0) out[0] = s[0];
}

extern "C" void kernel_launch(void* const* d_in, const int* in_sizes, int n_in,
                              void* d_out, int out_size, void* d_ws, size_t ws_size,
                              hipStream_t stream) {
    const float* x      = (const float*)d_in[0];
    const int*   ei     = (const int*)d_in[1];
    const int*   pos    = (const int*)d_in[2];
    const int*   neg    = (const int*)d_in[3];
    const float* gcn_w  = (const float*)d_in[4];
    const float* gcn_b  = (const float*)d_in[5];
    const float* pred_w = (const float*)d_in[6];
    const float* pred_b = (const float*)d_in[7];
    float* out = (float*)d_out;

    const int n = in_sizes[0] / DD;     // 50000
    const int e = in_sizes[1] / 2;      // 640000
    const int p = in_sizes[2] / 2;      // 100000
    const int nb = (n + 255) / 256;

    char* ws = (char*)d_ws;
    size_t off = 0;
    auto alloc = [&](size_t bytes) {
        void* ptr = ws + off;
        off += (bytes + 255) & ~(size_t)255;
        return ptr;
    };
    float* dinv      = (float*)alloc((size_t)n * 4);
    int*   counts    = (int*)alloc((size_t)n * 4);
    int*   rowptr    = (int*)alloc((size_t)(n + 1) * 4);
    int*   cursor    = (int*)alloc((size_t)n * 4);
    int*   partial   = (int*)alloc(256 * 4);
    int*   partial2  = (int*)alloc(256 * 4);
    float* lossPart  = (float*)alloc((size_t)4096 * 4);
    ushort* csr_src  = (ushort*)alloc((size_t)e * 2);
    ushort* wfrag    = (ushort*)alloc((size_t)3 * 2048 * 8 * 2);
    unsigned char* xq = (unsigned char*)alloc((size_t)n * 128);
    unsigned char* zq  = (unsigned char*)alloc((size_t)n * 384);
    unsigned char* zqw = (unsigned char*)alloc((size_t)n * 384);
    (void)ws_size;

    hipMemsetAsync(counts, 0, (size_t)n * 4, stream);

    count_kernel<<<(e + 255) / 256, 256, 0, stream>>>(counts, ei + e, e);
    scan_blocks<<<nb, 256, 0, stream>>>(counts, rowptr, partial, dinv, n);
    scan_partials<<<1, 256, 0, stream>>>(partial, partial2, nb);
    add_offsets<<<nb, 256, 0, stream>>>(rowptr, cursor, partial2, n, e);
    int blocksPerPart = (e + 255) / 256 / 2;
    fill_kernel<<<blocksPerPart * 8, 256, 0, stream>>>(ei, cursor, csr_src, e, n, blocksPerPart);

    size_t m8 = (size_t)n * 128 / 8;
    cvt_kernel<<<(int)((m8 + 255) / 256), 256, 0, stream>>>(x, xq, m8);
    wpack_kernel<<<24, 256, 0, stream>>>(gcn_w, wfrag);

    const int layerBlocks = n / 16;  // 3125
    for (int l = 0; l < 3; ++l) {
        const unsigned char* srcq = (l == 0) ? xq : (zq + (size_t)(l - 1) * 128);
        int srcStride = (l == 0) ? 128 : 384;
        layer_fused_kernel<<<layerBlocks, 256, 0, stream>>>(
            srcq, srcStride, rowptr, csr_src, dinv,
            wfrag + (size_t)l * 2048 * 8,
            gcn_b + (size_t)l * 128, pred_w + (size_t)l * 128,
            zq + (size_t)l * 128, zqw + (size_t)l * 128, n);
    }

    float inv_total = 1.0f / (2.0f * (float)p);
    int lossBlocks = (2 * p + 63) / 64;  // 3125
    loss_mfma_kernel<<<lossBlocks, 256, 0, stream>>>(
        zq, zqw, pos, neg, pred_b, lossPart, p, inv_total);
    loss_reduce_kernel<<<1, 256, 0, stream>>>(lossPart, out, lossBlocks);
}

// Round 19
// 237.336 us; speedup vs baseline: 1.1122x; 1.1122x over previous
//
#include <hip/hip_runtime.h>
#include <hip/hip_bf16.h>

#define DD 128

typedef __attribute__((ext_vector_type(8))) short short8;
typedef __attribute__((ext_vector_type(4))) float f32x4;
typedef __attribute__((ext_vector_type(2))) float f32x2;

static __device__ __forceinline__ int gtid() {
    return blockIdx.x * blockDim.x + threadIdx.x;
}

static __device__ __forceinline__ ushort f2bfu(float f) {
    __hip_bfloat16 h = __float2bfloat16(f);
    return *reinterpret_cast<ushort*>(&h);
}

// ---- fp8 e4m3fn encode/decode (manual fallback, RNE, subnormal-correct) ----
static __device__ __forceinline__ unsigned int fp8e(float f) {
    unsigned int s = (__float_as_uint(f) >> 31) << 7;
    float a = fabsf(f);
    if (a < 0.015625f) return s | (unsigned int)rintf(a * 512.0f);
    unsigned int u = __float_as_uint(a);
    u += 0x0007FFFFu + ((u >> 20) & 1u);
    unsigned int e8 = (u >> 23) - 120u;
    unsigned int m = (u >> 20) & 7u;
    if (e8 > 15u || (e8 == 15u && m == 7u)) return s | 0x7Eu;
    return s | (e8 << 3) | m;
}

static __device__ __forceinline__ float fp8d(unsigned int b) {
    unsigned int t = b & 0x7Fu;
    float v = (t >= 8u) ? __uint_as_float((t << 20) + 0x3C000000u)
                        : (float)t * 0.001953125f;
    return (b & 0x80u) ? -v : v;
}

static __device__ __forceinline__ unsigned int pk8x2(float a, float b) {
#if __has_builtin(__builtin_amdgcn_cvt_pk_fp8_f32)
    return (unsigned int)__builtin_amdgcn_cvt_pk_fp8_f32(a, b, 0, false);
#else
    return fp8e(a) | (fp8e(b) << 8);
#endif
}

static __device__ __forceinline__ unsigned int pk8x4(float a, float b, float c, float d) {
#if __has_builtin(__builtin_amdgcn_cvt_pk_fp8_f32)
    int v = __builtin_amdgcn_cvt_pk_fp8_f32(a, b, 0, false);
    v = __builtin_amdgcn_cvt_pk_fp8_f32(c, d, v, true);
    return (unsigned int)v;
#else
    return fp8e(a) | (fp8e(b) << 8) | (fp8e(c) << 16) | (fp8e(d) << 24);
#endif
}

static __device__ __forceinline__ void fp8x4_dec(unsigned int u, float* f) {
#if __has_builtin(__builtin_amdgcn_cvt_pk_f32_fp8)
    f32x2 lo = __builtin_amdgcn_cvt_pk_f32_fp8((int)u, false);
    f32x2 hi = __builtin_amdgcn_cvt_pk_f32_fp8((int)u, true);
    f[0] = lo[0]; f[1] = lo[1]; f[2] = hi[0]; f[3] = hi[1];
#else
    f[0] = fp8d(u & 0xFFu);
    f[1] = fp8d((u >> 8) & 0xFFu);
    f[2] = fp8d((u >> 16) & 0xFFu);
    f[3] = fp8d((u >> 24) & 0xFFu);
#endif
}

// ---------- degree / CSR build ----------

__global__ void count_kernel(int* __restrict__ counts, const int* __restrict__ dst, int e) {
    int i = gtid();
    if (i < e) atomicAdd(&counts[dst[i]], 1);
}

__global__ __launch_bounds__(256) void scan_blocks(const int* __restrict__ counts,
                                                   int* __restrict__ rowptr,
                                                   int* __restrict__ partial,
                                                   float* __restrict__ dinv, int n) {
    __shared__ int s[256];
    int i = blockIdx.x * 256 + threadIdx.x;
    int v = (i < n) ? counts[i] : 0;
    if (i < n) dinv[i] = rsqrtf(1.0f + (float)v);
    s[threadIdx.x] = v;
    __syncthreads();
    for (int off = 1; off < 256; off <<= 1) {
        int t = (threadIdx.x >= off) ? s[threadIdx.x - off] : 0;
        __syncthreads();
        s[threadIdx.x] += t;
        __syncthreads();
    }
    if (i < n) rowptr[i] = s[threadIdx.x] - v;
    if (threadIdx.x == 255) partial[blockIdx.x] = s[255];
}

__global__ __launch_bounds__(256) void scan_partials(int* __restrict__ partial,
                                                     int* __restrict__ partial2, int nb) {
    __shared__ int s[256];
    int v = (threadIdx.x < nb) ? partial[threadIdx.x] : 0;
    s[threadIdx.x] = v;
    __syncthreads();
    for (int off = 1; off < 256; off <<= 1) {
        int t = (threadIdx.x >= off) ? s[threadIdx.x - off] : 0;
        __syncthreads();
        s[threadIdx.x] += t;
        __syncthreads();
    }
    partial2[threadIdx.x] = s[threadIdx.x] - v;
}

__global__ __launch_bounds__(256) void add_offsets(int* __restrict__ rowptr,
                                                   int* __restrict__ cursor,
                                                   const int* __restrict__ partial2,
                                                   int n, int e) {
    int i = blockIdx.x * 256 + threadIdx.x;
    if (i < n) {
        int r = rowptr[i] + partial2[blockIdx.x];
        rowptr[i] = r;
        cursor[i] = r;
        if (i == n - 1) rowptr[n] = e;
    }
}

// dst-windowed scatter (R17)
__global__ __launch_bounds__(256) void fill_kernel(
    const int* __restrict__ ei, int* __restrict__ cursor,
    ushort* __restrict__ csr_src, int e, int n, int blocksPerPart) {
    int part = blockIdx.x & 7;
    int blk = blockIdx.x >> 3;
    int lo = (int)(((long)n * part) >> 3);
    int hi = (int)(((long)n * (part + 1)) >> 3);
    int stride = blocksPerPart * 256;
    for (int i = blk * 256 + threadIdx.x; i < e; i += stride) {
        int d = ei[e + i];
        if (d < lo || d >= hi) continue;
        int s = ei[i];
        int pos = atomicAdd(&cursor[d], 1);
        csr_src[pos] = (ushort)s;
    }
}

// ---------- x -> fp8 (vectorized: 8 elems/thread) ----------
__global__ void cvt_kernel(const float* __restrict__ x, unsigned char* __restrict__ xq, size_t m8) {
    size_t i = (size_t)blockIdx.x * blockDim.x + threadIdx.x;
    if (i >= m8) return;
    const float4* xp = reinterpret_cast<const float4*>(x + i * 8);
    float4 a = xp[0], b = xp[1];
    uint2 q;
    q.x = pk8x4(a.x, a.y, a.z, a.w);
    q.y = pk8x4(b.x, b.y, b.z, b.w);
    *reinterpret_cast<uint2*>(xq + i * 8) = q;
}

// ---------- W -> bf16 MFMA B-fragment order ----------
__global__ __launch_bounds__(256) void wpack_kernel(const float* __restrict__ gcn_w,
                                                    ushort* __restrict__ wfrag) {
    int tid = blockIdx.x * 256 + threadIdx.x;
    if (tid >= 3 * 4 * 8 * 64) return;
    int lane = tid & 63;
    int c = (tid >> 6) & 7;
    int s = (tid >> 9) & 3;
    int l = tid >> 11;
    const float* W = gcn_w + (size_t)l * 128 * 128;
    int col = c * 16 + (lane & 15);
    int k0 = s * 32 + (lane >> 4) * 8;
    ushort u[8];
#pragma unroll
    for (int j = 0; j < 8; ++j) {
        u[j] = f2bfu(W[(size_t)(k0 + j) * 128 + col]);
    }
    *reinterpret_cast<uint4*>(wfrag + (size_t)tid * 8) = *reinterpret_cast<const uint4*>(u);
}

// ---------- fused layer: 16 waves, one wave per row; then 8 waves GEMM ----------
// block = 1024 threads = 16 waves = 16 rows (3125 blocks, exact; 50000 agg waves).
// Phase 1: wave w aggregates row row0+w into swizzled LDS row w (bf16).
// Phase 2: waves 0..7 each compute one 16-col MFMA block; waves 8..15 exit.
// LDS swizzle: physical_byte(row, bo) = row*256 + (bo ^ ((row&7)<<4))
__global__ __launch_bounds__(1024) void layer_fused_kernel(
    const unsigned char* __restrict__ srcq, int srcStride,
    const int* __restrict__ rowptr, const ushort* __restrict__ csr_src,
    const float* __restrict__ dinv, const ushort* __restrict__ wfrag,
    const float* __restrict__ bias, const float* __restrict__ pwsl,
    unsigned char* __restrict__ zq_sl, unsigned char* __restrict__ zqw_sl, int n) {
    __shared__ unsigned char ah[16 * 256];
    int lane = threadIdx.x & 63;
    int wid = threadIdx.x >> 6;   // 0..15
    int row0 = blockIdx.x * 16;

    // ---- phase 1: wave wid aggregates row row0+wid ----
    {
        int g = lane >> 3;   // edge slot 0..7
        int c = lane & 7;    // feature chunk (16 feats)
        int row = row0 + wid;
        int j0 = rowptr[row], j1 = rowptr[row + 1];
        float dr = dinv[row];
        float acc[16];
#pragma unroll
        for (int k = 0; k < 16; ++k) acc[k] = 0.f;
        for (int j = j0 + g; j < j1; j += 8) {
            int s = (int)csr_src[j];
            float cf = dinv[s] * dr;
            uint4 v = *reinterpret_cast<const uint4*>(srcq + (size_t)s * srcStride + c * 16);
            float f[16];
            fp8x4_dec(v.x, f);
            fp8x4_dec(v.y, f + 4);
            fp8x4_dec(v.z, f + 8);
            fp8x4_dec(v.w, f + 12);
#pragma unroll
            for (int k = 0; k < 16; ++k) acc[k] = fmaf(cf, f[k], acc[k]);
        }
#pragma unroll
        for (int k = 0; k < 16; ++k) {
            acc[k] += __shfl_xor(acc[k], 8);
            acc[k] += __shfl_xor(acc[k], 16);
            acc[k] += __shfl_xor(acc[k], 32);
        }
        float d2 = dr * dr;
        uint4 sv = *reinterpret_cast<const uint4*>(srcq + (size_t)row * srcStride + c * 16);
        float sf[16];
        fp8x4_dec(sv.x, sf);
        fp8x4_dec(sv.y, sf + 4);
        fp8x4_dec(sv.z, sf + 8);
        fp8x4_dec(sv.w, sf + 12);
#pragma unroll
        for (int k = 0; k < 16; ++k) acc[k] = fmaf(d2, sf[k], acc[k]);
        if (g == 0) {
            unsigned int pk[8];
#pragma unroll
            for (int q = 0; q < 8; ++q) {
                pk[q] = (unsigned int)f2bfu(acc[2 * q]) | ((unsigned int)f2bfu(acc[2 * q + 1]) << 16);
            }
            int swz = (wid & 7) << 4;
            int bo = c * 32;
            *reinterpret_cast<uint4*>(ah + wid * 256 + (bo ^ swz)) =
                *reinterpret_cast<const uint4*>(pk);
            *reinterpret_cast<uint4*>(ah + wid * 256 + ((bo + 16) ^ swz)) =
                *reinterpret_cast<const uint4*>(pk + 4);
        }
    }
    __syncthreads();
    if (wid >= 8) return;

    // ---- phase 2: wave wid computes 16 cols [wid*16, wid*16+16) ----
    short8 bfr[4];
#pragma unroll
    for (int s = 0; s < 4; ++s) {
        bfr[s] = *reinterpret_cast<const short8*>(wfrag + ((size_t)(s * 8 + wid) * 64 + lane) * 8);
    }
    int rlo = lane & 15;
    int kg = lane >> 4;
    int swzr = (rlo & 7) << 4;
    const unsigned char* arow = ah + rlo * 256;
    short8 a0 = *reinterpret_cast<const short8*>(arow + ((kg * 16) ^ swzr));
    short8 a1 = *reinterpret_cast<const short8*>(arow + ((kg * 16 + 64) ^ swzr));
    short8 a2 = *reinterpret_cast<const short8*>(arow + ((kg * 16 + 128) ^ swzr));
    short8 a3 = *reinterpret_cast<const short8*>(arow + ((kg * 16 + 192) ^ swzr));
    f32x4 acc = {0.f, 0.f, 0.f, 0.f};
    acc = __builtin_amdgcn_mfma_f32_16x16x32_bf16(a0, bfr[0], acc, 0, 0, 0);
    acc = __builtin_amdgcn_mfma_f32_16x16x32_bf16(a1, bfr[1], acc, 0, 0, 0);
    acc = __builtin_amdgcn_mfma_f32_16x16x32_bf16(a2, bfr[2], acc, 0, 0, 0);
    acc = __builtin_amdgcn_mfma_f32_16x16x32_bf16(a3, bfr[3], acc, 0, 0, 0);

    int col = wid * 16 + rlo;
    float b0 = bias[col];
    float pw = pwsl[col] * 8.0f;
    int rowBase = row0 + kg * 4;
#pragma unroll
    for (int r = 0; r < 4; ++r) {
        float v = fmaxf(acc[r] + b0, 0.f);
        unsigned int q = pk8x2(v, v * pw);  // low byte: zq, high byte: zqw
        zq_sl[(size_t)(rowBase + r) * 384 + col] = (unsigned char)(q & 0xFFu);
        zqw_sl[(size_t)(rowBase + r) * 384 + col] = (unsigned char)((q >> 8) & 0xFFu);
    }
}

// ---------- loss: fp8 MFMA diagonal dot ----------
__global__ __launch_bounds__(256) void loss_mfma_kernel(
    const unsigned char* __restrict__ zq, const unsigned char* __restrict__ zqw,
    const int* __restrict__ pos, const int* __restrict__ neg,
    const float* __restrict__ pb, float* __restrict__ partialOut,
    int p, float inv_total) {
    __shared__ float red[4];
    int lane = threadIdx.x & 63;
    int wv = threadIdx.x >> 6;
    int pairBase = (blockIdx.x * 4 + wv) * 16;
    float term = 0.f;
    if (pairBase < 2 * p) {
        int m = lane & 15;
        int kg = lane >> 4;
        int pi = pairBase + m;
        int pic = (pi < 2 * p) ? pi : (2 * p - 1);
        bool isneg = (pic >= p);
        const int* pr = isneg ? neg : pos;
        int idx = isneg ? (pic - p) : pic;
        int a = pr[idx];
        int b = pr[p + idx];
        const long* pa = reinterpret_cast<const long*>(zq + (size_t)a * 384) + kg;
        const long* pbw = reinterpret_cast<const long*>(zqw + (size_t)b * 384) + kg;
        long av[12], bv[12];
#pragma unroll
        for (int s = 0; s < 12; ++s) av[s] = pa[s * 4];
#pragma unroll
        for (int s = 0; s < 12; ++s) bv[s] = pbw[s * 4];
        f32x4 acc = {0.f, 0.f, 0.f, 0.f};
#pragma unroll
        for (int s = 0; s < 12; ++s) {
            acc = __builtin_amdgcn_mfma_f32_16x16x32_fp8_fp8(av[s], bv[s], acc, 0, 0, 0);
        }
        bool isdiag = (lane >> 4) == ((lane & 15) >> 2);
        int r2 = lane & 3;
        float v = (r2 == 0) ? acc[0] : (r2 == 1) ? acc[1] : (r2 == 2) ? acc[2] : acc[3];
        if (isdiag && pi < 2 * p) {
            float logit = v * 0.125f + pb[0];
            float t = isneg ? logit : -logit;
            term = (fmaxf(t, 0.f) + log1pf(expf(-fabsf(t)))) * inv_total;
        }
    }
#pragma unroll
    for (int off = 1; off < 64; off <<= 1) term += __shfl_xor(term, off);
    if (lane == 0) red[wv] = term;
    __syncthreads();
    if (threadIdx.x == 0) partialOut[blockIdx.x] = red[0] + red[1] + red[2] + red[3];
}

__global__ __launch_bounds__(256) void loss_reduce_kernel(
    const float* __restrict__ partial, float* __restrict__ out, int m) {
    __shared__ float s[256];
    float a = 0.f;
    for (int i = threadIdx.x; i < m; i += 256) a += partial[i];
    s[threadIdx.x] = a;
    __syncthreads();
    for (int off = 128; off > 0; off >>= 1) {
        if (threadIdx.x < off) s[threadIdx.x] += s[threadIdx.x + off];
        __syncthreads();
    }
    if (threadIdx.x == 0) out[0] = s[0];
}

extern "C" void kernel_launch(void* const* d_in, const int* in_sizes, int n_in,
                              void* d_out, int out_size, void* d_ws, size_t ws_size,
                              hipStream_t stream) {
    const float* x      = (const float*)d_in[0];
    const int*   ei     = (const int*)d_in[1];
    const int*   pos    = (const int*)d_in[2];
    const int*   neg    = (const int*)d_in[3];
    const float* gcn_w  = (const float*)d_in[4];
    const float* gcn_b  = (const float*)d_in[5];
    const float* pred_w = (const float*)d_in[6];
    const float* pred_b = (const float*)d_in[7];
    float* out = (float*)d_out;

    const int n = in_sizes[0] / DD;     // 50000
    const int e = in_sizes[1] / 2;      // 640000
    const int p = in_sizes[2] / 2;      // 100000
    const int nb = (n + 255) / 256;

    char* ws = (char*)d_ws;
    size_t off = 0;
    auto alloc = [&](size_t bytes) {
        void* ptr = ws + off;
        off += (bytes + 255) & ~(size_t)255;
        return ptr;
    };
    float* dinv      = (float*)alloc((size_t)n * 4);
    int*   counts    = (int*)alloc((size_t)n * 4);
    int*   rowptr    = (int*)alloc((size_t)(n + 1) * 4);
    int*   cursor    = (int*)alloc((size_t)n * 4);
    int*   partial   = (int*)alloc(256 * 4);
    int*   partial2  = (int*)alloc(256 * 4);
    float* lossPart  = (float*)alloc((size_t)4096 * 4);
    ushort* csr_src  = (ushort*)alloc((size_t)e * 2);
    ushort* wfrag    = (ushort*)alloc((size_t)3 * 2048 * 8 * 2);
    unsigned char* xq = (unsigned char*)alloc((size_t)n * 128);
    unsigned char* zq  = (unsigned char*)alloc((size_t)n * 384);
    unsigned char* zqw = (unsigned char*)alloc((size_t)n * 384);
    (void)ws_size;

    hipMemsetAsync(counts, 0, (size_t)n * 4, stream);

    count_kernel<<<(e + 255) / 256, 256, 0, stream>>>(counts, ei + e, e);
    scan_blocks<<<nb, 256, 0, stream>>>(counts, rowptr, partial, dinv, n);
    scan_partials<<<1, 256, 0, stream>>>(partial, partial2, nb);
    add_offsets<<<nb, 256, 0, stream>>>(rowptr, cursor, partial2, n, e);
    int blocksPerPart = (e + 255) / 256 / 2;
    fill_kernel<<<blocksPerPart * 8, 256, 0, stream>>>(ei, cursor, csr_src, e, n, blocksPerPart);

    size_t m8 = (size_t)n * 128 / 8;
    cvt_kernel<<<(int)((m8 + 255) / 256), 256, 0, stream>>>(x, xq, m8);
    wpack_kernel<<<24, 256, 0, stream>>>(gcn_w, wfrag);

    const int layerBlocks = n / 16;  // 3125
    for (int l = 0; l < 3; ++l) {
        const unsigned char* srcq = (l == 0) ? xq : (zq + (size_t)(l - 1) * 128);
        int srcStride = (l == 0) ? 128 : 384;
        layer_fused_kernel<<<layerBlocks, 1024, 0, stream>>>(
            srcq, srcStride, rowptr, csr_src, dinv,
            wfrag + (size_t)l * 2048 * 8,
            gcn_b + (size_t)l * 128, pred_w + (size_t)l * 128,
            zq + (size_t)l * 128, zqw + (size_t)l * 128, n);
    }

    float inv_total = 1.0f / (2.0f * (float)p);
    int lossBlocks = (2 * p + 63) / 64;  // 3125
    loss_mfma_kernel<<<lossBlocks, 256, 0, stream>>>(
        zq, zqw, pos, neg, pred_b, lossPart, p, inv_total);
    loss_reduce_kernel<<<1, 256, 0, stream>>>(lossPart, out, lossBlocks);
}

// Round 21
// 234.961 us; speedup vs baseline: 1.1234x; 1.0101x over previous
//
#include <hip/hip_runtime.h>
#include <hip/hip_bf16.h>

#define DD 128

typedef __attribute__((ext_vector_type(8))) short short8;
typedef __attribute__((ext_vector_type(4))) float f32x4;
typedef __attribute__((ext_vector_type(2))) float f32x2;

static __device__ __forceinline__ int gtid() {
    return blockIdx.x * blockDim.x + threadIdx.x;
}

static __device__ __forceinline__ ushort f2bfu(float f) {
    __hip_bfloat16 h = __float2bfloat16(f);
    return *reinterpret_cast<ushort*>(&h);
}

// ---- fp8 e4m3fn encode/decode (manual fallback, RNE, subnormal-correct) ----
static __device__ __forceinline__ unsigned int fp8e(float f) {
    unsigned int s = (__float_as_uint(f) >> 31) << 7;
    float a = fabsf(f);
    if (a < 0.015625f) return s | (unsigned int)rintf(a * 512.0f);
    unsigned int u = __float_as_uint(a);
    u += 0x0007FFFFu + ((u >> 20) & 1u);
    unsigned int e8 = (u >> 23) - 120u;
    unsigned int m = (u >> 20) & 7u;
    if (e8 > 15u || (e8 == 15u && m == 7u)) return s | 0x7Eu;
    return s | (e8 << 3) | m;
}

static __device__ __forceinline__ float fp8d(unsigned int b) {
    unsigned int t = b & 0x7Fu;
    float v = (t >= 8u) ? __uint_as_float((t << 20) + 0x3C000000u)
                        : (float)t * 0.001953125f;
    return (b & 0x80u) ? -v : v;
}

static __device__ __forceinline__ unsigned int pk8x2(float a, float b) {
#if __has_builtin(__builtin_amdgcn_cvt_pk_fp8_f32)
    return (unsigned int)__builtin_amdgcn_cvt_pk_fp8_f32(a, b, 0, false);
#else
    return fp8e(a) | (fp8e(b) << 8);
#endif
}

static __device__ __forceinline__ unsigned int pk8x4(float a, float b, float c, float d) {
#if __has_builtin(__builtin_amdgcn_cvt_pk_fp8_f32)
    int v = __builtin_amdgcn_cvt_pk_fp8_f32(a, b, 0, false);
    v = __builtin_amdgcn_cvt_pk_fp8_f32(c, d, v, true);
    return (unsigned int)v;
#else
    return fp8e(a) | (fp8e(b) << 8) | (fp8e(c) << 16) | (fp8e(d) << 24);
#endif
}

// decode 2 fp8 bytes (lo or hi pair of a word) -> f32x2; HI is compile-time
template <bool HI>
static __device__ __forceinline__ f32x2 fp8pk(unsigned int u) {
#if __has_builtin(__builtin_amdgcn_cvt_pk_f32_fp8)
    return __builtin_amdgcn_cvt_pk_f32_fp8((int)u, HI);
#else
    f32x2 r;
    unsigned int base = HI ? (u >> 16) : u;
    r[0] = fp8d(base & 0xFFu);
    r[1] = fp8d((base >> 8) & 0xFFu);
    return r;
#endif
}

#if __has_builtin(__builtin_elementwise_fma)
#define PKFMA(a, b, c) __builtin_elementwise_fma(a, b, c)
#else
static __device__ __forceinline__ f32x2 PKFMA(f32x2 a, f32x2 b, f32x2 c) {
    f32x2 r;
    r[0] = fmaf(a[0], b[0], c[0]);
    r[1] = fmaf(a[1], b[1], c[1]);
    return r;
}
#endif

// ---------- degree / CSR build ----------

__global__ void count_kernel(int* __restrict__ counts, const int* __restrict__ dst, int e) {
    int i = gtid();
    if (i < e) atomicAdd(&counts[dst[i]], 1);
}

__global__ __launch_bounds__(256) void scan_blocks(const int* __restrict__ counts,
                                                   int* __restrict__ rowptr,
                                                   int* __restrict__ partial,
                                                   float* __restrict__ dinv, int n) {
    __shared__ int s[256];
    int i = blockIdx.x * 256 + threadIdx.x;
    int v = (i < n) ? counts[i] : 0;
    if (i < n) dinv[i] = rsqrtf(1.0f + (float)v);
    s[threadIdx.x] = v;
    __syncthreads();
    for (int off = 1; off < 256; off <<= 1) {
        int t = (threadIdx.x >= off) ? s[threadIdx.x - off] : 0;
        __syncthreads();
        s[threadIdx.x] += t;
        __syncthreads();
    }
    if (i < n) rowptr[i] = s[threadIdx.x] - v;
    if (threadIdx.x == 255) partial[blockIdx.x] = s[255];
}

__global__ __launch_bounds__(256) void scan_partials(int* __restrict__ partial,
                                                     int* __restrict__ partial2, int nb) {
    __shared__ int s[256];
    int v = (threadIdx.x < nb) ? partial[threadIdx.x] : 0;
    s[threadIdx.x] = v;
    __syncthreads();
    for (int off = 1; off < 256; off <<= 1) {
        int t = (threadIdx.x >= off) ? s[threadIdx.x - off] : 0;
        __syncthreads();
        s[threadIdx.x] += t;
        __syncthreads();
    }
    partial2[threadIdx.x] = s[threadIdx.x] - v;
}

__global__ __launch_bounds__(256) void add_offsets(int* __restrict__ rowptr,
                                                   int* __restrict__ cursor,
                                                   const int* __restrict__ partial2,
                                                   int n, int e) {
    int i = blockIdx.x * 256 + threadIdx.x;
    if (i < n) {
        int r = rowptr[i] + partial2[blockIdx.x];
        rowptr[i] = r;
        cursor[i] = r;
        if (i == n - 1) rowptr[n] = e;
    }
}

// dst-windowed scatter (R17)
__global__ __launch_bounds__(256) void fill_kernel(
    const int* __restrict__ ei, int* __restrict__ cursor,
    ushort* __restrict__ csr_src, int e, int n, int blocksPerPart) {
    int part = blockIdx.x & 7;
    int blk = blockIdx.x >> 3;
    int lo = (int)(((long)n * part) >> 3);
    int hi = (int)(((long)n * (part + 1)) >> 3);
    int stride = blocksPerPart * 256;
    for (int i = blk * 256 + threadIdx.x; i < e; i += stride) {
        int d = ei[e + i];
        if (d < lo || d >= hi) continue;
        int s = ei[i];
        int pos = atomicAdd(&cursor[d], 1);
        csr_src[pos] = (ushort)s;
    }
}

// ---------- x -> fp8 (vectorized: 8 elems/thread) ----------
__global__ void cvt_kernel(const float* __restrict__ x, unsigned char* __restrict__ xq, size_t m8) {
    size_t i = (size_t)blockIdx.x * blockDim.x + threadIdx.x;
    if (i >= m8) return;
    const float4* xp = reinterpret_cast<const float4*>(x + i * 8);
    float4 a = xp[0], b = xp[1];
    uint2 q;
    q.x = pk8x4(a.x, a.y, a.z, a.w);
    q.y = pk8x4(b.x, b.y, b.z, b.w);
    *reinterpret_cast<uint2*>(xq + i * 8) = q;
}

// ---------- W -> bf16 MFMA B-fragment order ----------
__global__ __launch_bounds__(256) void wpack_kernel(const float* __restrict__ gcn_w,
                                                    ushort* __restrict__ wfrag) {
    int tid = blockIdx.x * 256 + threadIdx.x;
    if (tid >= 3 * 4 * 8 * 64) return;
    int lane = tid & 63;
    int c = (tid >> 6) & 7;
    int s = (tid >> 9) & 3;
    int l = tid >> 11;
    const float* W = gcn_w + (size_t)l * 128 * 128;
    int col = c * 16 + (lane & 15);
    int k0 = s * 32 + (lane >> 4) * 8;
    ushort u[8];
#pragma unroll
    for (int j = 0; j < 8; ++j) {
        u[j] = f2bfu(W[(size_t)(k0 + j) * 128 + col]);
    }
    *reinterpret_cast<uint4*>(wfrag + (size_t)tid * 8) = *reinterpret_cast<const uint4*>(u);
}

// ---------- fused layer: 16 waves, one wave per row; then 8 waves GEMM ----------
// Phase-1 accumulation uses f32x2 packed FMA (v_pk_fma_f32).
__global__ __launch_bounds__(1024) void layer_fused_kernel(
    const unsigned char* __restrict__ srcq, int srcStride,
    const int* __restrict__ rowptr, const ushort* __restrict__ csr_src,
    const float* __restrict__ dinv, const ushort* __restrict__ wfrag,
    const float* __restrict__ bias, const float* __restrict__ pwsl,
    unsigned char* __restrict__ zq_sl, unsigned char* __restrict__ zqw_sl, int n) {
    __shared__ unsigned char ah[16 * 256];
    int lane = threadIdx.x & 63;
    int wid = threadIdx.x >> 6;   // 0..15
    int row0 = blockIdx.x * 16;

    // ---- phase 1: wave wid aggregates row row0+wid ----
    {
        int g = lane >> 3;   // edge slot 0..7
        int c = lane & 7;    // feature chunk (16 feats)
        int row = row0 + wid;
        int j0 = rowptr[row], j1 = rowptr[row + 1];
        float dr = dinv[row];
        f32x2 acc2[8];
#pragma unroll
        for (int k = 0; k < 8; ++k) acc2[k] = (f32x2){0.f, 0.f};
        for (int j = j0 + g; j < j1; j += 8) {
            int s = (int)csr_src[j];
            float cf = dinv[s] * dr;
            f32x2 cf2 = {cf, cf};
            uint4 v = *reinterpret_cast<const uint4*>(srcq + (size_t)s * srcStride + c * 16);
            acc2[0] = PKFMA(cf2, fp8pk<false>(v.x), acc2[0]);
            acc2[1] = PKFMA(cf2, fp8pk<true>(v.x), acc2[1]);
            acc2[2] = PKFMA(cf2, fp8pk<false>(v.y), acc2[2]);
            acc2[3] = PKFMA(cf2, fp8pk<true>(v.y), acc2[3]);
            acc2[4] = PKFMA(cf2, fp8pk<false>(v.z), acc2[4]);
            acc2[5] = PKFMA(cf2, fp8pk<true>(v.z), acc2[5]);
            acc2[6] = PKFMA(cf2, fp8pk<false>(v.w), acc2[6]);
            acc2[7] = PKFMA(cf2, fp8pk<true>(v.w), acc2[7]);
        }
        // self-loop
        {
            float d2 = dr * dr;
            f32x2 d22 = {d2, d2};
            uint4 sv = *reinterpret_cast<const uint4*>(srcq + (size_t)row * srcStride + c * 16);
            acc2[0] = PKFMA(d22, fp8pk<false>(sv.x), acc2[0]);
            acc2[1] = PKFMA(d22, fp8pk<true>(sv.x), acc2[1]);
            acc2[2] = PKFMA(d22, fp8pk<false>(sv.y), acc2[2]);
            acc2[3] = PKFMA(d22, fp8pk<true>(sv.y), acc2[3]);
            acc2[4] = PKFMA(d22, fp8pk<false>(sv.z), acc2[4]);
            acc2[5] = PKFMA(d22, fp8pk<true>(sv.z), acc2[5]);
            acc2[6] = PKFMA(d22, fp8pk<false>(sv.w), acc2[6]);
            acc2[7] = PKFMA(d22, fp8pk<true>(sv.w), acc2[7]);
        }
        float acc[16];
#pragma unroll
        for (int k = 0; k < 8; ++k) {
            acc[2 * k] = acc2[k][0];
            acc[2 * k + 1] = acc2[k][1];
        }
#pragma unroll
        for (int k = 0; k < 16; ++k) {
            acc[k] += __shfl_xor(acc[k], 8);
            acc[k] += __shfl_xor(acc[k], 16);
            acc[k] += __shfl_xor(acc[k], 32);
        }
        if (g == 0) {
            unsigned int pk[8];
#pragma unroll
            for (int q = 0; q < 8; ++q) {
                pk[q] = (unsigned int)f2bfu(acc[2 * q]) | ((unsigned int)f2bfu(acc[2 * q + 1]) << 16);
            }
            int swz = (wid & 7) << 4;
            int bo = c * 32;
            *reinterpret_cast<uint4*>(ah + wid * 256 + (bo ^ swz)) =
                *reinterpret_cast<const uint4*>(pk);
            *reinterpret_cast<uint4*>(ah + wid * 256 + ((bo + 16) ^ swz)) =
                *reinterpret_cast<const uint4*>(pk + 4);
        }
    }
    __syncthreads();
    if (wid >= 8) return;

    // ---- phase 2: wave wid computes 16 cols [wid*16, wid*16+16) ----
    short8 bfr[4];
#pragma unroll
    for (int s = 0; s < 4; ++s) {
        bfr[s] = *reinterpret_cast<const short8*>(wfrag + ((size_t)(s * 8 + wid) * 64 + lane) * 8);
    }
    int rlo = lane & 15;
    int kg = lane >> 4;
    int swzr = (rlo & 7) << 4;
    const unsigned char* arow = ah + rlo * 256;
    short8 a0 = *reinterpret_cast<const short8*>(arow + ((kg * 16) ^ swzr));
    short8 a1 = *reinterpret_cast<const short8*>(arow + ((kg * 16 + 64) ^ swzr));
    short8 a2 = *reinterpret_cast<const short8*>(arow + ((kg * 16 + 128) ^ swzr));
    short8 a3 = *reinterpret_cast<const short8*>(arow + ((kg * 16 + 192) ^ swzr));
    f32x4 acc = {0.f, 0.f, 0.f, 0.f};
    acc = __builtin_amdgcn_mfma_f32_16x16x32_bf16(a0, bfr[0], acc, 0, 0, 0);
    acc = __builtin_amdgcn_mfma_f32_16x16x32_bf16(a1, bfr[1], acc, 0, 0, 0);
    acc = __builtin_amdgcn_mfma_f32_16x16x32_bf16(a2, bfr[2], acc, 0, 0, 0);
    acc = __builtin_amdgcn_mfma_f32_16x16x32_bf16(a3, bfr[3], acc, 0, 0, 0);

    int col = wid * 16 + rlo;
    float b0 = bias[col];
    float pw = pwsl[col] * 8.0f;
    int rowBase = row0 + kg * 4;
#pragma unroll
    for (int r = 0; r < 4; ++r) {
        float v = fmaxf(acc[r] + b0, 0.f);
        unsigned int q = pk8x2(v, v * pw);  // low byte: zq, high byte: zqw
        zq_sl[(size_t)(rowBase + r) * 384 + col] = (unsigned char)(q & 0xFFu);
        zqw_sl[(size_t)(rowBase + r) * 384 + col] = (unsigned char)((q >> 8) & 0xFFu);
    }
}

// ---------- loss: fp8 MFMA diagonal dot ----------
__global__ __launch_bounds__(256) void loss_mfma_kernel(
    const unsigned char* __restrict__ zq, const unsigned char* __restrict__ zqw,
    const int* __restrict__ pos, const int* __restrict__ neg,
    const float* __restrict__ pb, float* __restrict__ partialOut,
    int p, float inv_total) {
    __shared__ float red[4];
    int lane = threadIdx.x & 63;
    int wv = threadIdx.x >> 6;
    int pairBase = (blockIdx.x * 4 + wv) * 16;
    float term = 0.f;
    if (pairBase < 2 * p) {
        int m = lane & 15;
        int kg = lane >> 4;
        int pi = pairBase + m;
        int pic = (pi < 2 * p) ? pi : (2 * p - 1);
        bool isneg = (pic >= p);
        const int* pr = isneg ? neg : pos;
        int idx = isneg ? (pic - p) : pic;
        int a = pr[idx];
        int b = pr[p + idx];
        const long* pa = reinterpret_cast<const long*>(zq + (size_t)a * 384) + kg;
        const long* pbw = reinterpret_cast<const long*>(zqw + (size_t)b * 384) + kg;
        long av[12], bv[12];
#pragma unroll
        for (int s = 0; s < 12; ++s) av[s] = pa[s * 4];
#pragma unroll
        for (int s = 0; s < 12; ++s) bv[s] = pbw[s * 4];
        f32x4 acc = {0.f, 0.f, 0.f, 0.f};
#pragma unroll
        for (int s = 0; s < 12; ++s) {
            acc = __builtin_amdgcn_mfma_f32_16x16x32_fp8_fp8(av[s], bv[s], acc, 0, 0, 0);
        }
        bool isdiag = (lane >> 4) == ((lane & 15) >> 2);
        int r2 = lane & 3;
        float v = (r2 == 0) ? acc[0] : (r2 == 1) ? acc[1] : (r2 == 2) ? acc[2] : acc[3];
        if (isdiag && pi < 2 * p) {
            float logit = v * 0.125f + pb[0];
            float t = isneg ? logit : -logit;
            term = (fmaxf(t, 0.f) + log1pf(expf(-fabsf(t)))) * inv_total;
        }
    }
#pragma unroll
    for (int off = 1; off < 64; off <<= 1) term += __shfl_xor(term, off);
    if (lane == 0) red[wv] = term;
    __syncthreads();
    if (threadIdx.x == 0) partialOut[blockIdx.x] = red[0] + red[1] + red[2] + red[3];
}

__global__ __launch_bounds__(256) void loss_reduce_kernel(
    const float* __restrict__ partial, float* __restrict__ out, int m) {
    __shared__ float s[256];
    float a = 0.f;
    for (int i = threadIdx.x; i < m; i += 256) a += partial[i];
    s[threadIdx.x] = a;
    __syncthreads();
    for (int off = 128; off > 0; off >>= 1) {
        if (threadIdx.x < off) s[threadIdx.x] += s[threadIdx.x + off];
        __syncthreads();
    }
    if (threadIdx.x == 0) out[0] = s[0];
}

extern "C" void kernel_launch(void* const* d_in, const int* in_sizes, int n_in,
                              void* d_out, int out_size, void* d_ws, size_t ws_size,
                              hipStream_t stream) {
    const float* x      = (const float*)d_in[0];
    const int*   ei     = (const int*)d_in[1];
    const int*   pos    = (const int*)d_in[2];
    const int*   neg    = (const int*)d_in[3];
    const float* gcn_w  = (const float*)d_in[4];
    const float* gcn_b  = (const float*)d_in[5];
    const float* pred_w = (const float*)d_in[6];
    const float* pred_b = (const float*)d_in[7];
    float* out = (float*)d_out;

    const int n = in_sizes[0] / DD;     // 50000
    const int e = in_sizes[1] / 2;      // 640000
    const int p = in_sizes[2] / 2;      // 100000
    const int nb = (n + 255) / 256;

    char* ws = (char*)d_ws;
    size_t off = 0;
    auto alloc = [&](size_t bytes) {
        void* ptr = ws + off;
        off += (bytes + 255) & ~(size_t)255;
        return ptr;
    };
    float* dinv      = (float*)alloc((size_t)n * 4);
    int*   counts    = (int*)alloc((size_t)n * 4);
    int*   rowptr    = (int*)alloc((size_t)(n + 1) * 4);
    int*   cursor    = (int*)alloc((size_t)n * 4);
    int*   partial   = (int*)alloc(256 * 4);
    int*   partial2  = (int*)alloc(256 * 4);
    float* lossPart  = (float*)alloc((size_t)4096 * 4);
    ushort* csr_src  = (ushort*)alloc((size_t)e * 2);
    ushort* wfrag    = (ushort*)alloc((size_t)3 * 2048 * 8 * 2);
    unsigned char* xq = (unsigned char*)alloc((size_t)n * 128);
    unsigned char* zq  = (unsigned char*)alloc((size_t)n * 384);
    unsigned char* zqw = (unsigned char*)alloc((size_t)n * 384);
    (void)ws_size;

    hipMemsetAsync(counts, 0, (size_t)n * 4, stream);

    count_kernel<<<(e + 255) / 256, 256, 0, stream>>>(counts, ei + e, e);
    scan_blocks<<<nb, 256, 0, stream>>>(counts, rowptr, partial, dinv, n);
    scan_partials<<<1, 256, 0, stream>>>(partial, partial2, nb);
    add_offsets<<<nb, 256, 0, stream>>>(rowptr, cursor, partial2, n, e);
    int blocksPerPart = (e + 255) / 256 / 2;
    fill_kernel<<<blocksPerPart * 8, 256, 0, stream>>>(ei, cursor, csr_src, e, n, blocksPerPart);

    size_t m8 = (size_t)n * 128 / 8;
    cvt_kernel<<<(int)((m8 + 255) / 256), 256, 0, stream>>>(x, xq, m8);
    wpack_kernel<<<24, 256, 0, stream>>>(gcn_w, wfrag);

    const int layerBlocks = n / 16;  // 3125
    for (int l = 0; l < 3; ++l) {
        const unsigned char* srcq = (l == 0) ? xq : (zq + (size_t)(l - 1) * 128);
        int srcStride = (l == 0) ? 128 : 384;
        layer_fused_kernel<<<layerBlocks, 1024, 0, stream>>>(
            srcq, srcStride, rowptr, csr_src, dinv,
            wfrag + (size_t)l * 2048 * 8,
            gcn_b + (size_t)l * 128, pred_w + (size_t)l * 128,
            zq + (size_t)l * 128, zqw + (size_t)l * 128, n);
    }

    float inv_total = 1.0f / (2.0f * (float)p);
    int lossBlocks = (2 * p + 63) / 64;  // 3125
    loss_mfma_kernel<<<lossBlocks, 256, 0, stream>>>(
        zq, zqw, pos, neg, pred_b, lossPart, p, inv_total);
    loss_reduce_kernel<<<1, 256, 0, stream>>>(lossPart, out, lossBlocks);
}